// Round 4
// baseline (322.896 us; speedup 1.0000x reference)
//
#include <hip/hip_runtime.h>

typedef unsigned short u16;
typedef unsigned int u32;
typedef __attribute__((ext_vector_type(8))) short short8_t;
typedef __attribute__((ext_vector_type(4))) float f32x4;

#define HID 2048
#define KVH 512
#define NROW 4096   // B*S
#define SC2 0.18033688011112042f   // (1/sqrt(64)) * log2(e)

__device__ __forceinline__ u16 f2bf(float f){
  u32 u = __builtin_bit_cast(u32, f);
  u += 0x7fffu + ((u >> 16) & 1u);   // round-to-nearest-even
  return (u16)(u >> 16);
}
__device__ __forceinline__ u32 cvtpk_bf16(float lo, float hi){
  u32 r; asm("v_cvt_pk_bf16_f32 %0, %1, %2" : "=v"(r) : "v"(lo), "v"(hi)); return r;
}

union FragAB { short8_t v; uint4 u4; uint2 q[2]; };

__device__ __forceinline__ void gload_lds16(const u16* g, u16* l){
  __builtin_amdgcn_global_load_lds((const __attribute__((address_space(1))) void*)g,
                                   (__attribute__((address_space(3))) void*)l, 16, 0, 0);
}

// ---------- prep: fp32 -> bf16 convert ----------
__global__ __launch_bounds__(256)
void conv_bf16(const float* __restrict__ X, u16* __restrict__ Y, int n4)
{
  for (int i = blockIdx.x * 256 + threadIdx.x; i < n4; i += gridDim.x * 256) {
    float4 v = ((const float4*)X)[i];
    ushort4 h; h.x = f2bf(v.x); h.y = f2bf(v.y); h.z = f2bf(v.z); h.w = f2bf(v.w);
    ((ushort4*)Y)[i] = h;
  }
}

// ---------- prep: W[K][N] fp32 -> Wt[N][K] bf16 ----------
__global__ __launch_bounds__(256)
void transpose_conv(const float* __restrict__ W, u16* __restrict__ Wt, int K, int N)
{
  __shared__ float tile[32][33];
  int x = blockIdx.x * 32 + threadIdx.x;
  int y0 = blockIdx.y * 32;
  #pragma unroll
  for (int j = threadIdx.y; j < 32; j += 8)
    tile[j][threadIdx.x] = W[(size_t)(y0 + j) * N + x];
  __syncthreads();
  #pragma unroll
  for (int j = threadIdx.y; j < 32; j += 8)
    Wt[(size_t)(blockIdx.x * 32 + j) * K + y0 + threadIdx.x] = f2bf(tile[threadIdx.x][j]);
}

// ---------- bf16 GEMM, B^T input (m97 structure) ----------
// C[M,N] = scale * A[M,K] @ Bt[N,K]^T.  128x128 tile, BK=64, global_load_lds,
// linear LDS, contiguous-sigma ds_read_b128 fragments, 4 waves 2x2.
// bx < nsplit uses (B0,C0) else (B1,C1). CT1: second half writes C^T
// (u16, leading stride NROW) with contiguous ushort4 row-quads.
template<int CBF, int CT1>
__global__ __launch_bounds__(256)
void gemm_bt(const u16* __restrict__ A, const u16* __restrict__ B0,
             const u16* __restrict__ B1, void* __restrict__ C0,
             void* __restrict__ C1, int nsplit, int N, int K, float scale)
{
  __shared__ __align__(16) u16 As[128 * 64];
  __shared__ __align__(16) u16 Bs[128 * 64];
  const int t = threadIdx.x, lane = t & 63, wid = t >> 6;
  const int wm = wid >> 1, wn = wid & 1;
  const int r = lane & 15, g = lane >> 4;
  const u16* Bt; char* Cp; int n0;
  if ((int)blockIdx.x < nsplit) { Bt = B0; Cp = (char*)C0; n0 = blockIdx.x * 128; }
  else { Bt = B1; Cp = (char*)C1; n0 = ((int)blockIdx.x - nsplit) * 128; }
  const int m0 = blockIdx.y * 128;

  f32x4 acc[4][4];
  #pragma unroll
  for (int i = 0; i < 4; i++)
    #pragma unroll
    for (int j = 0; j < 4; j++) acc[i][j] = (f32x4){0.f, 0.f, 0.f, 0.f};

  const u16* Arow = A + (size_t)m0 * K;
  const u16* Brow = Bt + (size_t)n0 * K;
  const int lrow = t >> 3, lcol = (t & 7) * 8;

  for (int k0 = 0; k0 < K; k0 += 64) {
    __syncthreads();
    #pragma unroll
    for (int c = 0; c < 4; ++c) {
      gload_lds16(Arow + (size_t)(c * 32 + lrow) * K + k0 + lcol, As + c * 2048 + wid * 512);
      gload_lds16(Brow + (size_t)(c * 32 + lrow) * K + k0 + lcol, Bs + c * 2048 + wid * 512);
    }
    __syncthreads();
    #pragma unroll
    for (int kk = 0; kk < 64; kk += 32) {
      FragAB a[4], b[4];
      #pragma unroll
      for (int mi = 0; mi < 4; mi++)
        a[mi].u4 = *(const uint4*)&As[(wm * 64 + mi * 16 + r) * 64 + kk + g * 8];
      #pragma unroll
      for (int ni = 0; ni < 4; ni++)
        b[ni].u4 = *(const uint4*)&Bs[(wn * 64 + ni * 16 + r) * 64 + kk + g * 8];
      #pragma unroll
      for (int mi = 0; mi < 4; mi++)
        #pragma unroll
        for (int ni = 0; ni < 4; ni++)
          acc[mi][ni] = __builtin_amdgcn_mfma_f32_16x16x32_bf16(a[mi].v, b[ni].v, acc[mi][ni], 0, 0, 0);
    }
  }
  if (CT1 && (int)blockIdx.x >= nsplit) {
    // transposed write: Ct[col][row], 4 consecutive rows per lane -> ushort4
    u16* Ct = (u16*)Cp;
    #pragma unroll
    for (int mi = 0; mi < 4; mi++) {
      int row = m0 + wm * 64 + mi * 16 + g * 4;
      #pragma unroll
      for (int ni = 0; ni < 4; ni++) {
        int col = n0 + wn * 64 + ni * 16 + r;
        ushort4 hv;
        hv.x = f2bf(acc[mi][ni][0] * scale); hv.y = f2bf(acc[mi][ni][1] * scale);
        hv.z = f2bf(acc[mi][ni][2] * scale); hv.w = f2bf(acc[mi][ni][3] * scale);
        *(ushort4*)&Ct[(size_t)col * NROW + row] = hv;
      }
    }
  } else {
    #pragma unroll
    for (int mi = 0; mi < 4; mi++) {
      int row = m0 + wm * 64 + mi * 16 + g * 4;
      #pragma unroll
      for (int ni = 0; ni < 4; ni++) {
        int col = n0 + wn * 64 + ni * 16 + r;
        #pragma unroll
        for (int rr = 0; rr < 4; rr++) {
          if (CBF) ((u16*)Cp)[(size_t)(row + rr) * N + col] = f2bf(acc[mi][ni][rr] * scale);
          else     ((float*)Cp)[(size_t)(row + rr) * N + col] = acc[mi][ni][rr];
        }
      }
    }
  }
}

// ---------- MFMA flash attention, swapped-operand layout ----------
// 4 waves, QBLK=128 (32 q-rows/wave, Q in regs, pre-scaled by SC2 in Q-gemm).
// Swapped QK^T -> in-lane softmax (2 shuffles). Defer-max (THR=8 log2). P packed
// via v_cvt_pk_bf16_f32 in-register. V^T comes pre-transposed from the V-gemm.
__global__ __launch_bounds__(256)
void attn_mfma(const u16* __restrict__ Q, const u16* __restrict__ K,
               const u16* __restrict__ VT, u16* __restrict__ O)
{
  __shared__ __align__(16) u16 Ks[64 * 72];   // [key][dim] pad-72
  __shared__ __align__(16) u16 Vt[64 * 72];   // [dim][key] pad-72
  const int qb = blockIdx.x, h = blockIdx.y, b = blockIdx.z;
  const int kvh = h >> 2;
  const int t = threadIdx.x, lane = t & 63, w = t >> 6;
  const int r = lane & 15, g = lane >> 4;

  FragAB qf[2][2];
  {
    const u16* Qg = Q + ((size_t)(b * 2048 + qb * 128 + w * 32)) * 2048 + h * 64;
    #pragma unroll
    for (int mb = 0; mb < 2; mb++)
      #pragma unroll
      for (int ks = 0; ks < 2; ks++)
        qf[mb][ks].u4 = *(const uint4*)(Qg + (size_t)(mb * 16 + r) * 2048 + ks * 32 + g * 8);
  }

  float m_run[2] = {-1e30f, -1e30f}, l_run[2] = {0.f, 0.f};
  f32x4 o[2][4];
  #pragma unroll
  for (int mb = 0; mb < 2; mb++)
    #pragma unroll
    for (int nd = 0; nd < 4; nd++) o[mb][nd] = (f32x4){0.f, 0.f, 0.f, 0.f};

  const u16* Kg0 = K + (size_t)(b * 2048) * 512 + kvh * 64;
  const u16* Vg0 = VT + (size_t)(kvh * 64) * NROW + b * 2048;
  const int ntiles = 2 * qb + 2;
  const int srow = t >> 3, scol = (t & 7) * 8;

  for (int jt = 0; jt < ntiles; ++jt) {
    __syncthreads();
    {  // stage K [key][dim] and V^T [dim][key] — both linear 16B copies
      const u16* Kg = Kg0 + (size_t)(jt * 64) * 512;
      *(uint4*)&Ks[srow * 72 + scol] = *(const uint4*)(Kg + (size_t)srow * 512 + scol);
      *(uint4*)&Ks[(srow + 32) * 72 + scol] = *(const uint4*)(Kg + (size_t)(srow + 32) * 512 + scol);
      const u16* Vg = Vg0 + jt * 64;
      *(uint4*)&Vt[srow * 72 + scol] = *(const uint4*)(Vg + (size_t)srow * NROW + scol);
      *(uint4*)&Vt[(srow + 32) * 72 + scol] = *(const uint4*)(Vg + (size_t)(srow + 32) * NROW + scol);
    }
    __syncthreads();

    if (jt * 64 <= qb * 128 + w * 32 + 31) {  // wave participates
      // QK^T swapped: st[mb][kb][i] = S[qrow = mb*16+r][key = jt*64 + kb*16 + g*4 + i]
      f32x4 st[2][4];
      #pragma unroll
      for (int mb = 0; mb < 2; mb++)
        #pragma unroll
        for (int kb = 0; kb < 4; kb++) st[mb][kb] = (f32x4){0.f, 0.f, 0.f, 0.f};
      #pragma unroll
      for (int ks = 0; ks < 2; ks++) {
        FragAB kf[4];
        #pragma unroll
        for (int kb = 0; kb < 4; kb++)
          kf[kb].u4 = *(const uint4*)&Ks[(kb * 16 + r) * 72 + ks * 32 + g * 8];
        #pragma unroll
        for (int mb = 0; mb < 2; mb++)
          #pragma unroll
          for (int kb = 0; kb < 4; kb++)
            st[mb][kb] = __builtin_amdgcn_mfma_f32_16x16x32_bf16(kf[kb].v, qf[mb][ks].v, st[mb][kb], 0, 0, 0);
      }

      FragAB pa[2][2];
      #pragma unroll
      for (int mb = 0; mb < 2; mb++) {
        const int rowg = qb * 128 + w * 32 + mb * 16 + r;
        float sl[4][4];
        #pragma unroll
        for (int kb = 0; kb < 4; kb++)
          #pragma unroll
          for (int i = 0; i < 4; i++) sl[kb][i] = st[mb][kb][i];
        if (jt * 64 + 63 > qb * 128 + w * 32 + mb * 16) {   // tile crosses diagonal
          const int kdel = jt * 64 + g * 4 - rowg;
          #pragma unroll
          for (int kb = 0; kb < 4; kb++)
            #pragma unroll
            for (int i = 0; i < 4; i++)
              if (kdel + kb * 16 + i > 0) sl[kb][i] = -1e30f;
        }
        float pm = sl[0][0];
        #pragma unroll
        for (int kb = 0; kb < 4; kb++)
          #pragma unroll
          for (int i = 0; i < 4; i++) pm = fmaxf(pm, sl[kb][i]);
        pm = fmaxf(pm, __shfl_xor(pm, 16));
        pm = fmaxf(pm, __shfl_xor(pm, 32));
        // defer-max: only rescale when the running max grows by > 8 (log2)
        if (__any(pm > m_run[mb] + 8.f)) {
          float mn = fmaxf(m_run[mb], pm);
          float corr = __builtin_exp2f(m_run[mb] - mn);
          m_run[mb] = mn;
          l_run[mb] *= corr;
          #pragma unroll
          for (int nd = 0; nd < 4; nd++)
            #pragma unroll
            for (int i = 0; i < 4; i++) o[mb][nd][i] *= corr;
        }
        float p[4][4]; float ls = 0.f;
        #pragma unroll
        for (int kb = 0; kb < 4; kb++)
          #pragma unroll
          for (int i = 0; i < 4; i++) { p[kb][i] = __builtin_exp2f(sl[kb][i] - m_run[mb]); ls += p[kb][i]; }
        ls += __shfl_xor(ls, 16);
        ls += __shfl_xor(ls, 32);
        l_run[mb] += ls;
        #pragma unroll
        for (int ks = 0; ks < 2; ks++) {
          pa[mb][ks].q[0] = make_uint2(cvtpk_bf16(p[2 * ks][0], p[2 * ks][1]),
                                       cvtpk_bf16(p[2 * ks][2], p[2 * ks][3]));
          pa[mb][ks].q[1] = make_uint2(cvtpk_bf16(p[2 * ks + 1][0], p[2 * ks + 1][1]),
                                       cvtpk_bf16(p[2 * ks + 1][2], p[2 * ks + 1][3]));
        }
      }

      // PV swapped: o^T += V^T @ P^T  (o[mb][nd][i] = O[qrow=mb*16+r][d=nd*16+g*4+i])
      #pragma unroll
      for (int ks = 0; ks < 2; ks++) {
        FragAB vf[4];
        #pragma unroll
        for (int nd = 0; nd < 4; nd++) {
          const u16* base = &Vt[(nd * 16 + r) * 72 + ks * 32 + g * 4];
          vf[nd].q[0] = *(const uint2*)(base);
          vf[nd].q[1] = *(const uint2*)(base + 16);
        }
        #pragma unroll
        for (int mb = 0; mb < 2; mb++)
          #pragma unroll
          for (int nd = 0; nd < 4; nd++)
            o[mb][nd] = __builtin_amdgcn_mfma_f32_16x16x32_bf16(vf[nd].v, pa[mb][ks].v, o[mb][nd], 0, 0, 0);
      }
    }
  }

  u16* Og = O + ((size_t)(b * 2048 + qb * 128 + w * 32)) * 2048 + h * 64;
  #pragma unroll
  for (int mb = 0; mb < 2; mb++) {
    float inv = 1.f / l_run[mb];
    #pragma unroll
    for (int nd = 0; nd < 4; nd++) {
      ushort4 hv;
      hv.x = f2bf(o[mb][nd][0] * inv); hv.y = f2bf(o[mb][nd][1] * inv);
      hv.z = f2bf(o[mb][nd][2] * inv); hv.w = f2bf(o[mb][nd][3] * inv);
      *(ushort4*)(Og + (size_t)(mb * 16 + r) * 2048 + nd * 16 + g * 4) = hv;
    }
  }
}

extern "C" void kernel_launch(void* const* d_in, const int* in_sizes, int n_in,
                              void* d_out, int out_size, void* d_ws, size_t ws_size,
                              hipStream_t stream)
{
  (void)in_sizes; (void)n_in; (void)out_size; (void)ws_size;
  const float* X  = (const float*)d_in[0];
  const float* Wq = (const float*)d_in[1];
  const float* Wk = (const float*)d_in[2];
  const float* Wv = (const float*)d_in[3];
  const float* Wo = (const float*)d_in[4];
  float* out = (float*)d_out;

  // ws layout (u16), ~54.6 MB with aliasing
  u16* Xb  = (u16*)d_ws;                         // [4096][2048]
  u16* Qb  = Xb  + (size_t)NROW * HID;           // [4096][2048] (pre-scaled by SC2)
  u16* Kb  = Qb  + (size_t)NROW * HID;           // [4096][512]
  u16* VTb = Kb  + (size_t)NROW * KVH;           // [512][4096]  (V transposed)
  u16* Wqt = VTb + (size_t)NROW * KVH;           // [2048][2048]
  u16* Wkt = Wqt + (size_t)HID * HID;            // [512][2048]
  u16* Wvt = Wkt + (size_t)HID * KVH;
  u16* AOb = Xb;    // alias: X dead after KV gemm
  u16* Wot = Wqt;   // alias: Wqt dead after Q gemm

  conv_bf16<<<2048, 256, 0, stream>>>(X, Xb, NROW * HID / 4);
  transpose_conv<<<dim3(64, 64), dim3(32, 8), 0, stream>>>(Wq, Wqt, HID, HID);
  transpose_conv<<<dim3(16, 64), dim3(32, 8), 0, stream>>>(Wk, Wkt, HID, KVH);
  transpose_conv<<<dim3(16, 64), dim3(32, 8), 0, stream>>>(Wv, Wvt, HID, KVH);
  gemm_bt<1, 0><<<dim3(16, 32), 256, 0, stream>>>(Xb, Wqt, Wqt, Qb, Qb, 16, HID, HID, SC2);
  gemm_bt<1, 1><<<dim3(8, 32), 256, 0, stream>>>(Xb, Wkt, Wvt, Kb, VTb, 4, KVH, HID, 1.f);
  transpose_conv<<<dim3(64, 64), dim3(32, 8), 0, stream>>>(Wo, Wot, HID, HID);
  attn_mfma<<<dim3(16, 32, 2), 256, 0, stream>>>(Qb, Kb, VTb, AOb);
  gemm_bt<0, 0><<<dim3(16, 32), 256, 0, stream>>>(AOb, Wot, Wot, out, out, 16, HID, HID, 1.f);
}

// Round 5
// 261.364 us; speedup vs baseline: 1.2354x; 1.2354x over previous
//
#include <hip/hip_runtime.h>

typedef unsigned short u16;
typedef unsigned int u32;
typedef __attribute__((ext_vector_type(8))) short short8_t;
typedef __attribute__((ext_vector_type(4))) float f32x4;

#define HID 2048
#define KVH 512
#define NROW 4096   // B*S
#define SC2 0.18033688011112042f   // (1/sqrt(64)) * log2(e)

__device__ __forceinline__ u16 f2bf(float f){
  u32 u = __builtin_bit_cast(u32, f);
  u += 0x7fffu + ((u >> 16) & 1u);   // round-to-nearest-even
  return (u16)(u >> 16);
}
__device__ __forceinline__ u32 cvtpk_bf16(float lo, float hi){
  u32 r; asm("v_cvt_pk_bf16_f32 %0, %1, %2" : "=v"(r) : "v"(lo), "v"(hi)); return r;
}

union FragAB { short8_t v; uint4 u4; uint2 q[2]; };

__device__ __forceinline__ void gload_lds16(const u16* g, u16* l){
  __builtin_amdgcn_global_load_lds((const __attribute__((address_space(1))) void*)g,
                                   (__attribute__((address_space(3))) void*)l, 16, 0, 0);
}

// ---------- prep: fp32 -> bf16 convert ----------
__global__ __launch_bounds__(256)
void conv_bf16(const float* __restrict__ X, u16* __restrict__ Y, int n4)
{
  for (int i = blockIdx.x * 256 + threadIdx.x; i < n4; i += gridDim.x * 256) {
    float4 v = ((const float4*)X)[i];
    ushort4 h; h.x = f2bf(v.x); h.y = f2bf(v.y); h.z = f2bf(v.z); h.w = f2bf(v.w);
    ((ushort4*)Y)[i] = h;
  }
}

// ---------- prep: W[K][N] fp32 -> Wt[N][K] bf16 ----------
__global__ __launch_bounds__(256)
void transpose_conv(const float* __restrict__ W, u16* __restrict__ Wt, int K, int N)
{
  __shared__ float tile[32][33];
  int x = blockIdx.x * 32 + threadIdx.x;
  int y0 = blockIdx.y * 32;
  #pragma unroll
  for (int j = threadIdx.y; j < 32; j += 8)
    tile[j][threadIdx.x] = W[(size_t)(y0 + j) * N + x];
  __syncthreads();
  #pragma unroll
  for (int j = threadIdx.y; j < 32; j += 8)
    Wt[(size_t)(blockIdx.x * 32 + j) * K + y0 + threadIdx.x] = f2bf(tile[threadIdx.x][j]);
}

// ---------- bf16 GEMM, B^T input (m97 structure) ----------
template<int CBF, int CT1>
__global__ __launch_bounds__(256)
void gemm_bt(const u16* __restrict__ A, const u16* __restrict__ B0,
             const u16* __restrict__ B1, void* __restrict__ C0,
             void* __restrict__ C1, int nsplit, int N, int K, float scale)
{
  __shared__ __align__(16) u16 As[128 * 64];
  __shared__ __align__(16) u16 Bs[128 * 64];
  const int t = threadIdx.x, lane = t & 63, wid = t >> 6;
  const int wm = wid >> 1, wn = wid & 1;
  const int r = lane & 15, g = lane >> 4;
  const u16* Bt; char* Cp; int n0;
  if ((int)blockIdx.x < nsplit) { Bt = B0; Cp = (char*)C0; n0 = blockIdx.x * 128; }
  else { Bt = B1; Cp = (char*)C1; n0 = ((int)blockIdx.x - nsplit) * 128; }
  const int m0 = blockIdx.y * 128;

  f32x4 acc[4][4];
  #pragma unroll
  for (int i = 0; i < 4; i++)
    #pragma unroll
    for (int j = 0; j < 4; j++) acc[i][j] = (f32x4){0.f, 0.f, 0.f, 0.f};

  const u16* Arow = A + (size_t)m0 * K;
  const u16* Brow = Bt + (size_t)n0 * K;
  const int lrow = t >> 3, lcol = (t & 7) * 8;

  for (int k0 = 0; k0 < K; k0 += 64) {
    __syncthreads();
    #pragma unroll
    for (int c = 0; c < 4; ++c) {
      gload_lds16(Arow + (size_t)(c * 32 + lrow) * K + k0 + lcol, As + c * 2048 + wid * 512);
      gload_lds16(Brow + (size_t)(c * 32 + lrow) * K + k0 + lcol, Bs + c * 2048 + wid * 512);
    }
    __syncthreads();
    #pragma unroll
    for (int kk = 0; kk < 64; kk += 32) {
      FragAB a[4], b[4];
      #pragma unroll
      for (int mi = 0; mi < 4; mi++)
        a[mi].u4 = *(const uint4*)&As[(wm * 64 + mi * 16 + r) * 64 + kk + g * 8];
      #pragma unroll
      for (int ni = 0; ni < 4; ni++)
        b[ni].u4 = *(const uint4*)&Bs[(wn * 64 + ni * 16 + r) * 64 + kk + g * 8];
      #pragma unroll
      for (int mi = 0; mi < 4; mi++)
        #pragma unroll
        for (int ni = 0; ni < 4; ni++)
          acc[mi][ni] = __builtin_amdgcn_mfma_f32_16x16x32_bf16(a[mi].v, b[ni].v, acc[mi][ni], 0, 0, 0);
    }
  }
  if (CT1 && (int)blockIdx.x >= nsplit) {
    u16* Ct = (u16*)Cp;
    #pragma unroll
    for (int mi = 0; mi < 4; mi++) {
      int row = m0 + wm * 64 + mi * 16 + g * 4;
      #pragma unroll
      for (int ni = 0; ni < 4; ni++) {
        int col = n0 + wn * 64 + ni * 16 + r;
        ushort4 hv;
        hv.x = f2bf(acc[mi][ni][0] * scale); hv.y = f2bf(acc[mi][ni][1] * scale);
        hv.z = f2bf(acc[mi][ni][2] * scale); hv.w = f2bf(acc[mi][ni][3] * scale);
        *(ushort4*)&Ct[(size_t)col * NROW + row] = hv;
      }
    }
  } else {
    #pragma unroll
    for (int mi = 0; mi < 4; mi++) {
      int row = m0 + wm * 64 + mi * 16 + g * 4;
      #pragma unroll
      for (int ni = 0; ni < 4; ni++) {
        int col = n0 + wn * 64 + ni * 16 + r;
        #pragma unroll
        for (int rr = 0; rr < 4; rr++) {
          if (CBF) ((u16*)Cp)[(size_t)(row + rr) * N + col] = f2bf(acc[mi][ni][rr] * scale);
          else     ((float*)Cp)[(size_t)(row + rr) * N + col] = acc[mi][ni][rr];
        }
      }
    }
  }
}

// ---------- MFMA flash attention ----------
// Swapped-operand QK^T/PV, in-lane softmax, defer-max, cvt_pk P-packing.
// Double-buffered K/V LDS with async-staged (issue-early / write-late) loads:
// one barrier per KV tile; HBM latency hides under compute.
__device__ __forceinline__ void attn_block(const u16* __restrict__ Q, const u16* __restrict__ K,
    const u16* __restrict__ VT, u16* __restrict__ O,
    u16* Ks0, u16* Vt0, u16* Ks1, u16* Vt1, int qb, int h, int b)
{
  const int t = threadIdx.x, lane = t & 63, w = t >> 6;
  const int r = lane & 15, g = lane >> 4;
  const int kvh = h >> 2;

  FragAB qf[2][2];
  {
    const u16* Qg = Q + ((size_t)(b * 2048 + qb * 128 + w * 32)) * 2048 + h * 64;
    #pragma unroll
    for (int mb = 0; mb < 2; mb++)
      #pragma unroll
      for (int ks = 0; ks < 2; ks++)
        qf[mb][ks].u4 = *(const uint4*)(Qg + (size_t)(mb * 16 + r) * 2048 + ks * 32 + g * 8);
  }

  float m_run[2] = {-1e30f, -1e30f}, l_run[2] = {0.f, 0.f};
  f32x4 o[2][4];
  #pragma unroll
  for (int mb = 0; mb < 2; mb++)
    #pragma unroll
    for (int nd = 0; nd < 4; nd++) o[mb][nd] = (f32x4){0.f, 0.f, 0.f, 0.f};

  const u16* Kg0 = K + (size_t)(b * 2048) * 512 + kvh * 64;
  const u16* Vg0 = VT + (size_t)(kvh * 64) * NROW + b * 2048;
  const int nt = 2 * qb + 2;
  const int srow = t >> 3, scol = (t & 7) * 8;

  uint4 kr0, kr1, vr0, vr1;   // staging registers (issue-early / write-late)
  auto loadt = [&](int jt) {
    const u16* Kg = Kg0 + (size_t)(jt * 64) * 512;
    kr0 = *(const uint4*)(Kg + (size_t)srow * 512 + scol);
    kr1 = *(const uint4*)(Kg + (size_t)(srow + 32) * 512 + scol);
    const u16* Vg = Vg0 + jt * 64;
    vr0 = *(const uint4*)(Vg + (size_t)srow * NROW + scol);
    vr1 = *(const uint4*)(Vg + (size_t)(srow + 32) * NROW + scol);
  };
  auto writet = [&](u16* Ks, u16* Vt) {
    *(uint4*)&Ks[srow * 72 + scol] = kr0;
    *(uint4*)&Ks[(srow + 32) * 72 + scol] = kr1;
    *(uint4*)&Vt[srow * 72 + scol] = vr0;
    *(uint4*)&Vt[(srow + 32) * 72 + scol] = vr1;
  };

  loadt(0);
  writet(Ks0, Vt0);
  __syncthreads();

  for (int jt = 0; jt < nt; ++jt) {
    u16* Ks = (jt & 1) ? Ks1 : Ks0;
    u16* Vt = (jt & 1) ? Vt1 : Vt0;
    if (jt + 1 < nt) loadt(jt + 1);   // issue next-tile loads; consumed at writet

    if (jt * 64 <= qb * 128 + w * 32 + 31) {  // wave participates
      f32x4 st[2][4];
      #pragma unroll
      for (int mb = 0; mb < 2; mb++)
        #pragma unroll
        for (int kb = 0; kb < 4; kb++) st[mb][kb] = (f32x4){0.f, 0.f, 0.f, 0.f};
      #pragma unroll
      for (int ks = 0; ks < 2; ks++) {
        FragAB kf[4];
        #pragma unroll
        for (int kb = 0; kb < 4; kb++)
          kf[kb].u4 = *(const uint4*)&Ks[(kb * 16 + r) * 72 + ks * 32 + g * 8];
        #pragma unroll
        for (int mb = 0; mb < 2; mb++)
          #pragma unroll
          for (int kb = 0; kb < 4; kb++)
            st[mb][kb] = __builtin_amdgcn_mfma_f32_16x16x32_bf16(kf[kb].v, qf[mb][ks].v, st[mb][kb], 0, 0, 0);
      }

      FragAB pa[2][2];
      #pragma unroll
      for (int mb = 0; mb < 2; mb++) {
        const int rowg = qb * 128 + w * 32 + mb * 16 + r;
        float sl[4][4];
        #pragma unroll
        for (int kb = 0; kb < 4; kb++)
          #pragma unroll
          for (int i = 0; i < 4; i++) sl[kb][i] = st[mb][kb][i];
        if (jt * 64 + 63 > qb * 128 + w * 32 + mb * 16) {   // tile crosses diagonal
          const int kdel = jt * 64 + g * 4 - rowg;
          #pragma unroll
          for (int kb = 0; kb < 4; kb++)
            #pragma unroll
            for (int i = 0; i < 4; i++)
              if (kdel + kb * 16 + i > 0) sl[kb][i] = -1e30f;
        }
        float pm = sl[0][0];
        #pragma unroll
        for (int kb = 0; kb < 4; kb++)
          #pragma unroll
          for (int i = 0; i < 4; i++) pm = fmaxf(pm, sl[kb][i]);
        pm = fmaxf(pm, __shfl_xor(pm, 16));
        pm = fmaxf(pm, __shfl_xor(pm, 32));
        if (__any(pm > m_run[mb] + 8.f)) {   // defer-max rescale
          float mn = fmaxf(m_run[mb], pm);
          float corr = __builtin_exp2f(m_run[mb] - mn);
          m_run[mb] = mn;
          l_run[mb] *= corr;
          #pragma unroll
          for (int nd = 0; nd < 4; nd++)
            #pragma unroll
            for (int i = 0; i < 4; i++) o[mb][nd][i] *= corr;
        }
        float p[4][4]; float ls = 0.f;
        #pragma unroll
        for (int kb = 0; kb < 4; kb++)
          #pragma unroll
          for (int i = 0; i < 4; i++) { p[kb][i] = __builtin_exp2f(sl[kb][i] - m_run[mb]); ls += p[kb][i]; }
        ls += __shfl_xor(ls, 16);
        ls += __shfl_xor(ls, 32);
        l_run[mb] += ls;
        #pragma unroll
        for (int ks = 0; ks < 2; ks++) {
          pa[mb][ks].q[0] = make_uint2(cvtpk_bf16(p[2 * ks][0], p[2 * ks][1]),
                                       cvtpk_bf16(p[2 * ks][2], p[2 * ks][3]));
          pa[mb][ks].q[1] = make_uint2(cvtpk_bf16(p[2 * ks + 1][0], p[2 * ks + 1][1]),
                                       cvtpk_bf16(p[2 * ks + 1][2], p[2 * ks + 1][3]));
        }
      }

      #pragma unroll
      for (int ks = 0; ks < 2; ks++) {
        FragAB vf[4];
        #pragma unroll
        for (int nd = 0; nd < 4; nd++) {
          const u16* base = &Vt[(nd * 16 + r) * 72 + ks * 32 + g * 4];
          vf[nd].q[0] = *(const uint2*)(base);
          vf[nd].q[1] = *(const uint2*)(base + 16);
        }
        #pragma unroll
        for (int mb = 0; mb < 2; mb++)
          #pragma unroll
          for (int nd = 0; nd < 4; nd++)
            o[mb][nd] = __builtin_amdgcn_mfma_f32_16x16x32_bf16(vf[nd].v, pa[mb][ks].v, o[mb][nd], 0, 0, 0);
      }
    }

    if (jt + 1 < nt) writet((jt & 1) ? Ks0 : Ks1, (jt & 1) ? Vt0 : Vt1);
    __syncthreads();   // one barrier per tile: all waves done with iter jt
  }

  u16* Og = O + ((size_t)(b * 2048 + qb * 128 + w * 32)) * 2048 + h * 64;
  #pragma unroll
  for (int mb = 0; mb < 2; mb++) {
    float inv = 1.f / l_run[mb];
    #pragma unroll
    for (int nd = 0; nd < 4; nd++) {
      ushort4 hv;
      hv.x = f2bf(o[mb][nd][0] * inv); hv.y = f2bf(o[mb][nd][1] * inv);
      hv.z = f2bf(o[mb][nd][2] * inv); hv.w = f2bf(o[mb][nd][3] * inv);
      *(ushort4*)(Og + (size_t)(mb * 16 + r) * 2048 + nd * 16 + g * 4) = hv;
    }
  }
}

// Paired q-blocks (bx, 15-bx): constant 34 tile-units per block.
__global__ __launch_bounds__(256)
void attn_mfma(const u16* __restrict__ Q, const u16* __restrict__ K,
               const u16* __restrict__ VT, u16* __restrict__ O)
{
  __shared__ __align__(16) u16 Ks0[64 * 72];
  __shared__ __align__(16) u16 Vt0[64 * 72];
  __shared__ __align__(16) u16 Ks1[64 * 72];
  __shared__ __align__(16) u16 Vt1[64 * 72];
  const int h = blockIdx.y, b = blockIdx.z;
  attn_block(Q, K, VT, O, Ks0, Vt0, Ks1, Vt1, (int)blockIdx.x, h, b);
  attn_block(Q, K, VT, O, Ks0, Vt0, Ks1, Vt1, 15 - (int)blockIdx.x, h, b);
}

extern "C" void kernel_launch(void* const* d_in, const int* in_sizes, int n_in,
                              void* d_out, int out_size, void* d_ws, size_t ws_size,
                              hipStream_t stream)
{
  (void)in_sizes; (void)n_in; (void)out_size; (void)ws_size;
  const float* X  = (const float*)d_in[0];
  const float* Wq = (const float*)d_in[1];
  const float* Wk = (const float*)d_in[2];
  const float* Wv = (const float*)d_in[3];
  const float* Wo = (const float*)d_in[4];
  float* out = (float*)d_out;

  u16* Xb  = (u16*)d_ws;                         // [4096][2048]
  u16* Qb  = Xb  + (size_t)NROW * HID;           // [4096][2048] (pre-scaled by SC2)
  u16* Kb  = Qb  + (size_t)NROW * HID;           // [4096][512]
  u16* VTb = Kb  + (size_t)NROW * KVH;           // [512][4096]  (V transposed)
  u16* Wqt = VTb + (size_t)NROW * KVH;           // [2048][2048]
  u16* Wkt = Wqt + (size_t)HID * HID;            // [512][2048]
  u16* Wvt = Wkt + (size_t)HID * KVH;
  u16* AOb = Xb;    // alias: X dead after KV gemm
  u16* Wot = Wqt;   // alias: Wqt dead after Q gemm

  conv_bf16<<<2048, 256, 0, stream>>>(X, Xb, NROW * HID / 4);
  transpose_conv<<<dim3(64, 64), dim3(32, 8), 0, stream>>>(Wq, Wqt, HID, HID);
  transpose_conv<<<dim3(16, 64), dim3(32, 8), 0, stream>>>(Wk, Wkt, HID, KVH);
  transpose_conv<<<dim3(16, 64), dim3(32, 8), 0, stream>>>(Wv, Wvt, HID, KVH);
  gemm_bt<1, 0><<<dim3(16, 32), 256, 0, stream>>>(Xb, Wqt, Wqt, Qb, Qb, 16, HID, HID, SC2);
  gemm_bt<1, 1><<<dim3(8, 32), 256, 0, stream>>>(Xb, Wkt, Wvt, Kb, VTb, 4, KVH, HID, 1.f);
  transpose_conv<<<dim3(64, 64), dim3(32, 8), 0, stream>>>(Wo, Wot, HID, HID);
  attn_mfma<<<dim3(8, 32, 2), 256, 0, stream>>>(Qb, Kb, VTb, AOb);
  gemm_bt<0, 0><<<dim3(16, 32), 256, 0, stream>>>(AOb, Wot, Wot, out, out, 16, HID, HID, 1.f);
}